// Round 4
// baseline (79.353 us; speedup 1.0000x reference)
//
#include <hip/hip_runtime.h>
#include <math.h>

#define C_IN 80
#define L_IN 3000
#define OUT_C 512
#define TL 128
#define NT1 256
#define NT2 512

typedef float floatx4 __attribute__((ext_vector_type(4)));

struct c2f { float x, y; };

__device__ __forceinline__ c2f cmul(c2f a, c2f b) {
    return { a.x*b.x - a.y*b.y, a.x*b.y + a.y*b.x };
}
__device__ __forceinline__ c2f csel(c2f a, c2f b, int bit) {
    c2f r; r.x = bit ? b.x : a.x; r.y = bit ? b.y : a.y; return r;
}
__device__ __forceinline__ float quadform(const float4* __restrict__ A, float4 p) {
    float4 r0 = A[0], r1 = A[1], r2 = A[2], r3 = A[3];
    return p.x*(r0.x*p.x + r0.y*p.y + r0.z*p.z + r0.w*p.w)
         + p.y*(r1.x*p.x + r1.y*p.y + r1.z*p.z + r1.w*p.w)
         + p.z*(r2.x*p.x + r2.y*p.y + r2.z*p.z + r2.w*p.w)
         + p.w*(r3.x*p.x + r3.y*p.y + r3.z*p.z + r3.w*p.w);
}

// ---------- K1: conv + quantum quadratic forms -> expz[b][l] (float4) ----------
__global__ __launch_bounds__(NT1) void qconv_expz_kernel(
    const float* __restrict__ x,
    const float* __restrict__ W_pre,
    const float* __restrict__ b_pre,
    const float* __restrict__ qw,
    float4* __restrict__ expz)
{
    __shared__ float4 s_wpre[C_IN*3];   // [ck] -> (q0,q1,q2,q3)
    __shared__ float4 s_A[4][4];        // A[q] rows over j'
    __shared__ float4 s_part[TL];       // conv partials from channel-half 1

    const int t  = threadIdx.x;
    const int b  = blockIdx.y;
    const int l0 = blockIdx.x * TL;

    for (int i = t; i < C_IN*3; i += NT1) {
        s_wpre[i] = make_float4(W_pre[0*C_IN*3 + i], W_pre[1*C_IN*3 + i],
                                W_pre[2*C_IN*3 + i], W_pre[3*C_IN*3 + i]);
    }
    __syncthreads();

    // wave 0 builds A (overlaps other waves' conv)
    if (t < 64) {
        c2f U[4][2][2];
        #pragma unroll
        for (int i = 0; i < 4; ++i) {
            float phi = qw[i*3+0], theta = qw[i*3+1], omega = qw[i*3+2];
            float sh, ch;  sincosf(0.5f*theta, &sh, &ch);
            float s1, c1;  sincosf(0.5f*(phi+omega), &s1, &c1);
            float s2, cv;  sincosf(0.5f*(phi-omega), &s2, &cv);
            U[i][0][0] = {  c1*ch, -s1*ch };   // em*c
            U[i][0][1] = { -cv*sh, -s2*sh };   // -ed*s
            U[i][1][0] = {  cv*sh, -s2*sh };   // edm*s
            U[i][1][1] = {  c1*ch,  s1*ch };   // ep*c
        }
        const int q  = t >> 4;
        const int j  = (t >> 2) & 3;
        const int jp = t & 3;
        const int j2  = (j  >> 1) & 1, j3  = j  & 1;
        const int jp2 = (jp >> 1) & 1, jp3 = jp & 1;
        float s = 0.f;
        #pragma unroll
        for (int k = 0; k < 16; ++k) {
            int m = k ^ ((k >> 1) & 1);        // CNOT(2,3)
            m ^= ((m >> 2) & 1) << 1;          // CNOT(1,2)
            m ^= ((m >> 3) & 1) << 2;          // CNOT(0,1)
            const int m0 = (m >> 3) & 1, m1 = (m >> 2) & 1;
            const int m2 = (m >> 1) & 1, m3 = m & 1;
            c2f w01 = cmul(U[0][m0][0], U[1][m1][0]);
            c2f av = cmul(w01, cmul(csel(U[2][m2][0], U[2][m2][1], j2),
                                    csel(U[3][m3][0], U[3][m3][1], j3)));
            c2f bv = cmul(w01, cmul(csel(U[2][m2][0], U[2][m2][1], jp2),
                                    csel(U[3][m3][0], U[3][m3][1], jp3)));
            float z = 1.f - 2.f * ((k >> (3 - q)) & 1);
            s += z * (av.x*bv.x + av.y*bv.y);
        }
        ((float*)s_A)[t] = s;
    }

    // conv: 2 threads per l, 40 channels each
    const int i = t & (TL - 1);
    const int h = t >> 7;
    const int l = l0 + i;
    const bool lvalid = (l < L_IN);

    float4 acc = (h == 0) ? make_float4(b_pre[0], b_pre[1], b_pre[2], b_pre[3])
                          : make_float4(0.f, 0.f, 0.f, 0.f);
    if (lvalid) {
        const float* __restrict__ xrow = x + (size_t)b * C_IN * L_IN + (size_t)(h*40) * L_IN + l;
        const bool has_m1 = (l >= 1);
        const bool has_p1 = (l + 1 < L_IN);
        #pragma unroll 4
        for (int c = 0; c < 40; ++c) {
            const float* r = xrow + c * L_IN;
            float xa = has_m1 ? r[-1] : 0.f;
            float xb = r[0];
            float xc = has_p1 ? r[1] : 0.f;
            float4 w0 = s_wpre[(h*40+c)*3+0], w1 = s_wpre[(h*40+c)*3+1], w2 = s_wpre[(h*40+c)*3+2];
            acc.x += w0.x*xa + w1.x*xb + w2.x*xc;
            acc.y += w0.y*xa + w1.y*xb + w2.y*xc;
            acc.z += w0.z*xa + w1.z*xb + w2.z*xc;
            acc.w += w0.w*xa + w1.w*xb + w2.w*xc;
        }
    }
    if (h == 1) s_part[i] = acc;
    __syncthreads();

    if (t < TL && lvalid) {
        float4 p = acc;
        float4 q2 = s_part[t];
        p.x += q2.x; p.y += q2.y; p.z += q2.z; p.w += q2.w;
        const float inv = 1.f / (p.x*p.x + p.y*p.y + p.z*p.z + p.w*p.w);
        float4 e;
        e.x = quadform(s_A[0], p) * inv;
        e.y = quadform(s_A[1], p) * inv;
        e.z = quadform(s_A[2], p) * inv;
        e.w = quadform(s_A[3], p) * inv;
        expz[(size_t)b * L_IN + l] = e;
    }
}

// ---------- K2: out[b,o,l] = W_post @ expz + b_post (write-bound) ----------
__global__ __launch_bounds__(NT2) void expand_kernel(
    const float4* __restrict__ expz,
    const float* __restrict__ W_post,
    const float* __restrict__ b_post,
    float* __restrict__ out)
{
    __shared__ float4 s_post[OUT_C];
    __shared__ float  s_bpost[OUT_C];

    const int t  = threadIdx.x;
    const int b  = blockIdx.y;
    const int l0 = blockIdx.x * TL;

    // NT2 == OUT_C: one thread per row
    s_post[t]  = *reinterpret_cast<const float4*>(&W_post[t*4]);
    s_bpost[t] = b_post[t];

    const int lane = t & 63;
    const int w    = t >> 6;        // wave 0..7
    const int lq   = lane & 31;     // l-quad within tile
    const int hi   = lane >> 5;     // 0/1: second o row
    const int l    = l0 + 4*lq;
    const bool v   = (l < L_IN);    // L_IN%4==0: l valid => whole quad valid

    float4 e0, e1, e2, e3;
    if (v) {
        const float4* ep = expz + (size_t)b * L_IN + l;
        e0 = ep[0]; e1 = ep[1]; e2 = ep[2]; e3 = ep[3];
    }
    __syncthreads();
    if (!v) return;

    float* op = out + (size_t)b * OUT_C * L_IN + (size_t)(w*2 + hi) * L_IN + l;
    #pragma unroll 8
    for (int k = 0; k < OUT_C/16; ++k) {
        const int o = w*2 + hi + 16*k;
        const float4 wv = s_post[o];
        const float  bb = s_bpost[o];
        floatx4 st;
        st.x = wv.x*e0.x + wv.y*e0.y + wv.z*e0.z + wv.w*e0.w + bb;
        st.y = wv.x*e1.x + wv.y*e1.y + wv.z*e1.z + wv.w*e1.w + bb;
        st.z = wv.x*e2.x + wv.y*e2.y + wv.z*e2.z + wv.w*e2.w + bb;
        st.w = wv.x*e3.x + wv.y*e3.y + wv.z*e3.z + wv.w*e3.w + bb;
        __builtin_nontemporal_store(st, reinterpret_cast<floatx4*>(op));
        op += (size_t)16 * L_IN;
    }
}

extern "C" void kernel_launch(void* const* d_in, const int* in_sizes, int n_in,
                              void* d_out, int out_size, void* d_ws, size_t ws_size,
                              hipStream_t stream) {
    const float* x      = (const float*)d_in[0];
    const float* W_pre  = (const float*)d_in[1];
    const float* b_pre  = (const float*)d_in[2];
    const float* W_post = (const float*)d_in[3];
    const float* b_post = (const float*)d_in[4];
    const float* qw     = (const float*)d_in[5];
    float* out = (float*)d_out;
    float4* expz = (float4*)d_ws;   // 32*3000*16B = 1.5 MB

    const int B = in_sizes[0] / (C_IN * L_IN);
    dim3 grid((L_IN + TL - 1) / TL, B);
    qconv_expz_kernel<<<grid, NT1, 0, stream>>>(x, W_pre, b_pre, qw, expz);
    expand_kernel<<<grid, NT2, 0, stream>>>(expz, W_post, b_post, out);
}

// Round 5
// 43.814 us; speedup vs baseline: 1.8112x; 1.8112x over previous
//
#include <hip/hip_runtime.h>
#include <math.h>

#define C_IN 80
#define L_IN 3000
#define OUT_C 512
#define NT 512       // 8 waves
#define TL 128       // l positions per block
#define CPT 20       // channels per thread in conv (4 threads per l)

struct c2f { float x, y; };

__device__ __forceinline__ c2f cmul(c2f a, c2f b) {
    return { a.x*b.x - a.y*b.y, a.x*b.y + a.y*b.x };
}
__device__ __forceinline__ c2f csel(c2f a, c2f b, int bit) {
    c2f r; r.x = bit ? b.x : a.x; r.y = bit ? b.y : a.y; return r;
}
__device__ __forceinline__ float quadform(const float4* __restrict__ A, float4 p) {
    float4 r0 = A[0], r1 = A[1], r2 = A[2], r3 = A[3];
    return p.x*(r0.x*p.x + r0.y*p.y + r0.z*p.z + r0.w*p.w)
         + p.y*(r1.x*p.x + r1.y*p.y + r1.z*p.z + r1.w*p.w)
         + p.z*(r2.x*p.x + r2.y*p.y + r2.z*p.z + r2.w*p.w)
         + p.w*(r3.x*p.x + r3.y*p.y + r3.z*p.z + r3.w*p.w);
}

__global__ __launch_bounds__(NT) void qconv_kernel(
    const float* __restrict__ x,
    const float* __restrict__ W_pre,
    const float* __restrict__ b_pre,
    const float* __restrict__ W_post,
    const float* __restrict__ b_post,
    const float* __restrict__ qw,
    float* __restrict__ out)
{
    __shared__ float4 s_wpre[C_IN*3];    // [ck] -> (q0,q1,q2,q3)
    __shared__ float4 s_post[OUT_C];     // W_post rows
    __shared__ float  s_bpost[OUT_C];
    __shared__ float4 s_A[4][4];         // A[q] rows over j'
    __shared__ float4 s_part[3][TL];     // conv partials from halves 1..3
    __shared__ float4 s_e[TL];           // expz per l

    const int t  = threadIdx.x;
    const int b  = blockIdx.y;
    const int l0 = blockIdx.x * TL;

    // ---- stage weights into LDS ----
    for (int i = t; i < C_IN*3; i += NT) {
        s_wpre[i] = make_float4(W_pre[0*C_IN*3 + i], W_pre[1*C_IN*3 + i],
                                W_pre[2*C_IN*3 + i], W_pre[3*C_IN*3 + i]);
    }
    if (t < OUT_C) {
        s_post[t]  = *reinterpret_cast<const float4*>(&W_post[t*4]);
        s_bpost[t] = b_post[t];
    }
    __syncthreads();

    // ---- wave 0 builds A (overlaps other waves' conv) ----
    if (t < 64) {
        c2f U[4][2][2];
        #pragma unroll
        for (int i = 0; i < 4; ++i) {
            float phi = qw[i*3+0], theta = qw[i*3+1], omega = qw[i*3+2];
            float sh, ch;  sincosf(0.5f*theta, &sh, &ch);
            float s1, c1;  sincosf(0.5f*(phi+omega), &s1, &c1);
            float s2, cv;  sincosf(0.5f*(phi-omega), &s2, &cv);
            U[i][0][0] = {  c1*ch, -s1*ch };   // em*c
            U[i][0][1] = { -cv*sh, -s2*sh };   // -ed*s
            U[i][1][0] = {  cv*sh, -s2*sh };   // edm*s
            U[i][1][1] = {  c1*ch,  s1*ch };   // ep*c
        }
        const int q  = t >> 4;
        const int j  = (t >> 2) & 3;
        const int jp = t & 3;
        const int j2  = (j  >> 1) & 1, j3  = j  & 1;
        const int jp2 = (jp >> 1) & 1, jp3 = jp & 1;
        float s = 0.f;
        #pragma unroll
        for (int k = 0; k < 16; ++k) {
            int m = k ^ ((k >> 1) & 1);        // CNOT(2,3)
            m ^= ((m >> 2) & 1) << 1;          // CNOT(1,2)
            m ^= ((m >> 3) & 1) << 2;          // CNOT(0,1)
            const int m0 = (m >> 3) & 1, m1 = (m >> 2) & 1;
            const int m2 = (m >> 1) & 1, m3 = m & 1;
            c2f w01 = cmul(U[0][m0][0], U[1][m1][0]);
            c2f av = cmul(w01, cmul(csel(U[2][m2][0], U[2][m2][1], j2),
                                    csel(U[3][m3][0], U[3][m3][1], j3)));
            c2f bv = cmul(w01, cmul(csel(U[2][m2][0], U[2][m2][1], jp2),
                                    csel(U[3][m3][0], U[3][m3][1], jp3)));
            float z = 1.f - 2.f * ((k >> (3 - q)) & 1);
            s += z * (av.x*bv.x + av.y*bv.y);
        }
        ((float*)s_A)[t] = s;
    }

    // ---- conv: 4 threads per l, 20 channels each ----
    const int i = t & (TL - 1);        // l index within tile
    const int h = t >> 7;              // channel quarter 0..3
    const int l = l0 + i;
    const bool lvalid = (l < L_IN);

    float4 acc = (h == 0) ? make_float4(b_pre[0], b_pre[1], b_pre[2], b_pre[3])
                          : make_float4(0.f, 0.f, 0.f, 0.f);
    if (lvalid) {
        const float* __restrict__ xrow = x + (size_t)b * C_IN * L_IN + (size_t)(h*CPT) * L_IN + l;
        const bool has_m1 = (l >= 1);
        const bool has_p1 = (l + 1 < L_IN);
        #pragma unroll 4
        for (int c = 0; c < CPT; ++c) {
            const float* r = xrow + c * L_IN;
            float xa = has_m1 ? r[-1] : 0.f;
            float xb = r[0];
            float xc = has_p1 ? r[1] : 0.f;
            const int ck = (h*CPT + c) * 3;
            float4 w0 = s_wpre[ck], w1 = s_wpre[ck+1], w2 = s_wpre[ck+2];
            acc.x += w0.x*xa + w1.x*xb + w2.x*xc;
            acc.y += w0.y*xa + w1.y*xb + w2.y*xc;
            acc.z += w0.z*xa + w1.z*xb + w2.z*xc;
            acc.w += w0.w*xa + w1.w*xb + w2.w*xc;
        }
    }
    if (h > 0) s_part[h-1][i] = acc;
    __syncthreads();   // partials + A visible

    // ---- expz via quadratic forms (threads 0..127, one per l) ----
    if (t < TL && lvalid) {
        float4 p = acc;
        float4 p1 = s_part[0][t], p2 = s_part[1][t], p3 = s_part[2][t];
        p.x += p1.x + p2.x + p3.x;
        p.y += p1.y + p2.y + p3.y;
        p.z += p1.z + p2.z + p3.z;
        p.w += p1.w + p2.w + p3.w;
        const float inv = 1.f / (p.x*p.x + p.y*p.y + p.z*p.z + p.w*p.w);
        float4 e;
        e.x = quadform(s_A[0], p) * inv;
        e.y = quadform(s_A[1], p) * inv;
        e.z = quadform(s_A[2], p) * inv;
        e.w = quadform(s_A[3], p) * inv;
        s_e[t] = e;
    }
    __syncthreads();   // e visible

    // ---- store: wave w handles o = w + 8k; lane owns one float2 column ----
    {
        const int lane = t & 63;
        const int w    = t >> 6;               // 0..7
        const int lc   = l0 + 2*lane;          // even; lc valid => lc+1 valid
        const bool v2  = (lc < L_IN);
        const float4 e0 = s_e[2*lane];
        const float4 e1 = s_e[2*lane + 1];
        float* op = out + (size_t)b * OUT_C * L_IN + (size_t)w * L_IN + lc;
        #pragma unroll 8
        for (int k = 0; k < OUT_C/8; ++k) {
            const int o = w + 8*k;
            float4 wv = s_post[o];
            float bb  = s_bpost[o];
            float2 st;
            st.x = wv.x*e0.x + wv.y*e0.y + wv.z*e0.z + wv.w*e0.w + bb;
            st.y = wv.x*e1.x + wv.y*e1.y + wv.z*e1.z + wv.w*e1.w + bb;
            if (v2) *reinterpret_cast<float2*>(op) = st;
            op += (size_t)8 * L_IN;
        }
    }
}

extern "C" void kernel_launch(void* const* d_in, const int* in_sizes, int n_in,
                              void* d_out, int out_size, void* d_ws, size_t ws_size,
                              hipStream_t stream) {
    const float* x      = (const float*)d_in[0];
    const float* W_pre  = (const float*)d_in[1];
    const float* b_pre  = (const float*)d_in[2];
    const float* W_post = (const float*)d_in[3];
    const float* b_post = (const float*)d_in[4];
    const float* qw     = (const float*)d_in[5];
    float* out = (float*)d_out;

    const int B = in_sizes[0] / (C_IN * L_IN);
    dim3 grid((L_IN + TL - 1) / TL, B);
    qconv_kernel<<<grid, NT, 0, stream>>>(x, W_pre, b_pre, W_post, b_post, qw, out);
}